// Round 1
// 544.949 us; speedup vs baseline: 1.2135x; 1.2135x over previous
//
#include <hip/hip_runtime.h>
#include <math.h>

#define Hdim    2048
#define HALF_H  1024
#define Bsz     4
#define Sdim    4096
#define Mrows   (Bsz * Sdim)        // 16384 rows per tensor

// ws float layout (total ~48 KB — well under previous 574 KB footprint):
//   [0,     8192)  : msum  (4 x 2048)  raw column sums of keys  -- memset 0
//   [8192, 12288)  : hpart (4 x 1024)  mean @ w1 accumulator    -- memset 0
//   [12288]        : rank_sel (int)
#define MSUM_OFF  0
#define HPART_OFF 8192
#define RANK_OFF  12288

// ---------------- K1: column sums of keys (atomic, full-GPU grid) ----------
// grid (4, 2, 64) = 512 blocks, block 256. 64 rows x 1024 cols per block.
__global__ void __launch_bounds__(256)
colsum_kernel(const float* __restrict__ keys, float* __restrict__ msum) {
    const int b  = blockIdx.x;
    const int cc = blockIdx.y;
    const int rb = blockIdx.z;                    // 0..63
    const int col = cc * 1024 + threadIdx.x * 4;
    const float* base = keys + ((size_t)(b * Sdim + rb * 64)) * Hdim + col;
    float4 acc = make_float4(0.f, 0.f, 0.f, 0.f);
    #pragma unroll 8
    for (int r = 0; r < 64; ++r) {
        const float4 v = *(const float4*)(base + (size_t)r * Hdim);
        acc.x += v.x; acc.y += v.y; acc.z += v.z; acc.w += v.w;
    }
    float* m = msum + b * Hdim + col;
    atomicAdd(m + 0, acc.x);
    atomicAdd(m + 1, acc.y);
    atomicAdd(m + 2, acc.z);
    atomicAdd(m + 3, acc.w);
}

// ---------------- K2: hpart[b][j] += (mean[b] @ w1)[j] ---------------------
// grid (4, 4, 16) = 256 blocks, block 256. mean = msum / Sdim folded here.
__global__ void __launch_bounds__(256)
mlp1_kernel(const float* __restrict__ msum, const float* __restrict__ w1,
            float* __restrict__ hpart) {
    const int b  = blockIdx.x;
    const int jb = blockIdx.y;
    const int kb = blockIdx.z;
    const int j  = jb * 256 + threadIdx.x;
    const int i0 = kb * 128;
    float acc = 0.f;
    #pragma unroll 8
    for (int i = i0; i < i0 + 128; ++i) {
        acc = fmaf(msum[b * Hdim + i], w1[(size_t)i * HALF_H + j], acc);
    }
    atomicAdd(&hpart[b * HALF_H + j], acc * (1.0f / (float)Sdim));
}

// ---------------- K3: relu, @w2, sigmoid, avg, threshold -> rank_sel -------
__global__ void __launch_bounds__(1024)
mlp2_kernel(const float* __restrict__ hpart, const float* __restrict__ b1,
            const float* __restrict__ w2, const float* __restrict__ b2,
            int* __restrict__ rank_sel) {
    const int j = threadIdx.x;                    // 0..1023
    const float bj = b1[j];
    const float wj = w2[j];
    float v[4];
    #pragma unroll
    for (int b = 0; b < 4; ++b)
        v[b] = fmaxf(hpart[b * HALF_H + j] + bj, 0.f) * wj;
    #pragma unroll
    for (int off = 32; off > 0; off >>= 1) {
        #pragma unroll
        for (int b = 0; b < 4; ++b) v[b] += __shfl_down(v[b], off, 64);
    }
    __shared__ float wp[16][4];
    const int wave = j >> 6, lane = j & 63;
    if (lane == 0) {
        #pragma unroll
        for (int b = 0; b < 4; ++b) wp[wave][b] = v[b];
    }
    __syncthreads();
    if (j == 0) {
        float avg = 0.f;
        #pragma unroll
        for (int b = 0; b < 4; ++b) {
            float s = b2[0];
            #pragma unroll
            for (int w = 0; w < 16; ++w) s += wp[w][b];
            avg += 1.0f / (1.0f + expf(-s));
        }
        avg *= 0.25f;
        *rank_sel = (avg >= 0.3f ? 1 : 0) + (avg >= 0.7f ? 1 : 0);
    }
}

// ---------------- K4: fused  out = x + ((x @ A) @ B) -----------------------
// One pass over x: read each row ONCE into registers, in-wave shuffle-fold
// for P = x@A, tiny LDS cross-wave reduce, apply with B held in registers.
// Block: 512 threads = 8 waves, thread owns 4 cols (c = tid*4), block owns a
// full 2048-wide strip of 64 rows processed in groups of G.
// Grid 512: blocks [0,256) -> keys, [256,512) -> values.
// Three instantiations (R=4/8/16) early-exit on rank_sel so the hot path
// keeps its own register budget (R<=8: <=128 VGPR -> 2 blocks/CU).
template <int IDX, int R, int G, int MINW>
__global__ void __launch_bounds__(512, MINW)
fused_kernel(const float* __restrict__ keys, const float* __restrict__ values,
             const float* __restrict__ kA, const float* __restrict__ kB,
             const float* __restrict__ vA, const float* __restrict__ vB,
             const int* __restrict__ rank_sel, float* __restrict__ out) {
    if (*rank_sel != IDX) return;

    __shared__ float lds_part[8][8][4][16];   // [g][wave][residue][j]
    __shared__ float lds_P[8][16];            // [g][j] final P row values

    const int tid  = threadIdx.x;
    const int lane = tid & 63;
    const int wid  = tid >> 6;
    const int blk  = blockIdx.x;
    const bool isK = blk < 256;
    const int rbase = (blk & 255) * 64;

    const float* __restrict__ X  = isK ? keys : values;
    const float* __restrict__ A  = isK ? kA : vA;   // [Hdim][R]
    const float* __restrict__ Bm = isK ? kB : vB;   // [R][Hdim]
    float* __restrict__ outp = out + (isK ? (size_t)0 : (size_t)Mrows * Hdim);

    const int c = tid * 4;

    // A fragment for this thread's 4 columns: areg[u][j] = A[c+u][j]
    float areg[4][R];
    #pragma unroll
    for (int u = 0; u < 4; ++u) {
        #pragma unroll
        for (int j = 0; j < R; ++j)
            areg[u][j] = A[(size_t)(c + u) * R + j];
    }
    // B fragment: breg[j] = B[j][c..c+3]
    float4 breg[R];
    #pragma unroll
    for (int j = 0; j < R; ++j)
        breg[j] = *(const float4*)(Bm + (size_t)j * Hdim + c);

    const float* Xb = X + (size_t)rbase * Hdim + c;
    float* Ob       = outp + (size_t)rbase * Hdim + c;

    for (int grp = 0; grp < 64 / G; ++grp) {
        // ---- load G rows of x (coalesced 8 KB/row across the block) ----
        float4 xg[G];
        #pragma unroll
        for (int g = 0; g < G; ++g)
            xg[g] = *(const float4*)(Xb + (size_t)(grp * G + g) * Hdim);

        // ---- phase 1: per-row partial P, fold 64 lanes -> 4 residues ----
        #pragma unroll
        for (int g = 0; g < G; ++g) {
            const float4 x = xg[g];
            float p[R];
            #pragma unroll
            for (int j = 0; j < R; ++j) {
                float t = x.x * areg[0][j];
                t = fmaf(x.y, areg[1][j], t);
                t = fmaf(x.z, areg[2][j], t);
                t = fmaf(x.w, areg[3][j], t);
                p[j] = t;
            }
            #pragma unroll
            for (int j = 0; j < R; ++j) {
                p[j] += __shfl_xor(p[j], 32, 64);
                p[j] += __shfl_xor(p[j], 16, 64);
                p[j] += __shfl_xor(p[j], 8, 64);
                p[j] += __shfl_xor(p[j], 4, 64);
            }
            if (lane < 4) {
                #pragma unroll
                for (int j = 0; j < R; ++j)
                    lds_part[g][wid][lane][j] = p[j];
            }
        }
        __syncthreads();

        // ---- phase 2: reduce 8 waves x 4 residues -> lds_P[g][j] --------
        if (tid < G * R) {
            const int g = tid / R, j = tid % R;    // R is a power of 2
            float s = 0.f;
            #pragma unroll
            for (int w = 0; w < 8; ++w) {
                s += (lds_part[g][w][0][j] + lds_part[g][w][1][j]) +
                     (lds_part[g][w][2][j] + lds_part[g][w][3][j]);
            }
            lds_P[g][j] = s;   // scale = SCALING*RESIDUAL_SCALE = 1.0
        }
        __syncthreads();

        // ---- phase 3: out = x + P @ B (B from registers), stream out ----
        #pragma unroll
        for (int g = 0; g < G; ++g) {
            float4 o = xg[g];
            #pragma unroll
            for (int j4 = 0; j4 < R / 4; ++j4) {
                const float4 pv = *(const float4*)&lds_P[g][j4 * 4];
                const float pj[4] = {pv.x, pv.y, pv.z, pv.w};
                #pragma unroll
                for (int q = 0; q < 4; ++q) {
                    const float4 bv = breg[j4 * 4 + q];
                    o.x = fmaf(pj[q], bv.x, o.x);
                    o.y = fmaf(pj[q], bv.y, o.y);
                    o.z = fmaf(pj[q], bv.z, o.z);
                    o.w = fmaf(pj[q], bv.w, o.w);
                }
            }
            *(float4*)(Ob + (size_t)(grp * G + g) * Hdim) = o;
        }
        // no trailing barrier needed: next group's phase-1 writes to
        // lds_part are ordered behind the phase-2 barrier above, and its
        // phase-2 writes to lds_P sit behind next group's first barrier.
    }
}

extern "C" void kernel_launch(void* const* d_in, const int* in_sizes, int n_in,
                              void* d_out, int out_size, void* d_ws, size_t ws_size,
                              hipStream_t stream) {
    const float* keys   = (const float*)d_in[0];
    const float* values = (const float*)d_in[1];
    const float* w1     = (const float*)d_in[2];
    const float* b1     = (const float*)d_in[3];
    const float* w2     = (const float*)d_in[4];
    const float* b2     = (const float*)d_in[5];
    const float* kA0 = (const float*)d_in[6];
    const float* kB0 = (const float*)d_in[7];
    const float* vA0 = (const float*)d_in[8];
    const float* vB0 = (const float*)d_in[9];
    const float* kA1 = (const float*)d_in[10];
    const float* kB1 = (const float*)d_in[11];
    const float* vA1 = (const float*)d_in[12];
    const float* vB1 = (const float*)d_in[13];
    const float* kA2 = (const float*)d_in[14];
    const float* kB2 = (const float*)d_in[15];
    const float* vA2 = (const float*)d_in[16];
    const float* vB2 = (const float*)d_in[17];

    float* ws_f    = (float*)d_ws;
    float* msum    = ws_f + MSUM_OFF;
    float* hpart   = ws_f + HPART_OFF;
    int*   ranksel = (int*)(ws_f + RANK_OFF);
    float* out     = (float*)d_out;

    // zero atomic accumulators (msum + hpart contiguous: 48 KB)
    hipMemsetAsync(msum, 0, (8192 + 4096) * sizeof(float), stream);

    colsum_kernel<<<dim3(Bsz, 2, 64), 256, 0, stream>>>(keys, msum);
    mlp1_kernel<<<dim3(Bsz, 4, 16), 256, 0, stream>>>(msum, w1, hpart);
    mlp2_kernel<<<1, 1024, 0, stream>>>(hpart, b1, w2, b2, ranksel);

    // exactly one of these proceeds past the rank_sel guard
    fused_kernel<0, 4, 8, 4><<<512, 512, 0, stream>>>(
        keys, values, kA0, kB0, vA0, vB0, ranksel, out);
    fused_kernel<1, 8, 4, 4><<<512, 512, 0, stream>>>(
        keys, values, kA1, kB1, vA1, vB1, ranksel, out);
    fused_kernel<2, 16, 8, 2><<<512, 512, 0, stream>>>(
        keys, values, kA2, kB2, vA2, vB2, ranksel, out);
}